// Round 1
// baseline (459.528 us; speedup 1.0000x reference)
//
#include <hip/hip_runtime.h>
#include <hip/hip_bf16.h>

#define DEV __device__ __forceinline__

typedef __bf16 bf16x8 __attribute__((ext_vector_type(8)));
typedef float  f32x4  __attribute__((ext_vector_type(4)));

// Problem constants (baked; capacities are compile-time fixed)
// caps = {512,1024,2048,4096,1024,512,2048,1024}, all multiples of 128
// row-tiles (128 tokens) cumulative: {0,4,12,28,60,68,72,88,96}

DEV unsigned short f2bf(float f) {
  union { float f; unsigned u; } v; v.f = f;
  unsigned u = v.u;
  unsigned r = (u + 0x7FFFu + ((u >> 16) & 1u)) >> 16;  // RNE
  return (unsigned short)r;
}

// XOR swizzle within an 8KB [128][32]-bf16 tile. Logical (row r, byte c in [0,64)).
// XORs addr bits [6:4] with a function of addr bits [9:7] -> bijection, 8B/16B aligned.
DEV int swz(int r, int cbyte) {
  return (r * 64 + cbyte) ^ (((r >> 1) & 7) << 4);
}

// C = A @ B^T + bias, per-expert B/bias. A: (12288 x K_) row-major (f32 or bf16),
// B: (E x N_ x K_) f32 row-major, C: (12288 x N_) (bf16 or f32).
template <int K_, int N_, int NCT_, bool A_BF16, bool OUT_BF16>
__global__ __launch_bounds__(256)
void gemm_expert(const void* __restrict__ Av, const float* __restrict__ Bw,
                 const float* __restrict__ bias, void* __restrict__ Cv) {
  __shared__ char lds[16384];
  char* As = lds;
  char* Bs = lds + 8192;

  const int t    = threadIdx.x;
  const int lane = t & 63;
  const int wv   = t >> 6;
  const int wr   = wv >> 1;      // wave row (0..1), 64 rows each
  const int wc   = wv & 1;       // wave col (0..1), 64 cols each
  const int fr   = lane & 15;    // fragment row/col index
  const int fq   = lane >> 4;    // k-chunk / output row quad

  const int rt = blockIdx.x / NCT_;          // global 128-row tile (0..95)
  const int ct = blockIdx.x - rt * NCT_;     // col tile

  // expert lookup from row-tile cumsum (caps/128 = {4,8,16,32,8,4,16,8})
  const int cums[9] = {0, 4, 12, 28, 60, 68, 72, 88, 96};
  int e = 0;
#pragma unroll
  for (int i = 1; i < 8; ++i) e += (rt >= cums[i]) ? 1 : 0;

  const int grow0 = rt * 128;   // global token row base
  const int nloc0 = ct * 128;   // expert-local col base
  const float* Bw_e   = Bw + (size_t)e * N_ * K_;
  const float* bias_e = bias + (size_t)e * N_;

  f32x4 acc[4][4];
#pragma unroll
  for (int i = 0; i < 4; ++i)
#pragma unroll
    for (int j = 0; j < 4; ++j) acc[i][j] = (f32x4){0.f, 0.f, 0.f, 0.f};

  for (int kb = 0; kb < K_; kb += 32) {
    __syncthreads();
    // ---- stage A-tile [128][32] and B-tile [128][32] into LDS as bf16 ----
#pragma unroll
    for (int it = 0; it < 4; ++it) {
      int q = t + it * 256;       // quad index 0..1023
      int r = q >> 3;             // tile row 0..127
      int c = (q & 7) * 4;        // elem col 0,4,..,28
      ushort4 va;
      if constexpr (A_BF16) {
        const unsigned short* s =
            (const unsigned short*)Av + (size_t)(grow0 + r) * K_ + kb + c;
        va = *(const ushort4*)s;
      } else {
        const float* s = (const float*)Av + (size_t)(grow0 + r) * K_ + kb + c;
        float4 f = *(const float4*)s;
        va.x = f2bf(f.x); va.y = f2bf(f.y); va.z = f2bf(f.z); va.w = f2bf(f.w);
      }
      *(ushort4*)(As + swz(r, c * 2)) = va;

      const float* s2 = Bw_e + (size_t)(nloc0 + r) * K_ + kb + c;
      float4 f2 = *(const float4*)s2;
      ushort4 vb;
      vb.x = f2bf(f2.x); vb.y = f2bf(f2.y); vb.z = f2bf(f2.z); vb.w = f2bf(f2.w);
      *(ushort4*)(Bs + swz(r, c * 2)) = vb;
    }
    __syncthreads();

    // ---- fragments + MFMA ----
    bf16x8 af[4], bfg[4];
#pragma unroll
    for (int mi = 0; mi < 4; ++mi) {
      int r = wr * 64 + mi * 16 + fr;
      af[mi] = *(bf16x8*)(As + swz(r, fq * 16));
    }
#pragma unroll
    for (int ni = 0; ni < 4; ++ni) {
      int r = wc * 64 + ni * 16 + fr;
      bfg[ni] = *(bf16x8*)(Bs + swz(r, fq * 16));
    }
#pragma unroll
    for (int mi = 0; mi < 4; ++mi)
#pragma unroll
      for (int ni = 0; ni < 4; ++ni)
        acc[mi][ni] = __builtin_amdgcn_mfma_f32_16x16x32_bf16(
            af[mi], bfg[ni], acc[mi][ni], 0, 0, 0);
  }

  // ---- epilogue: bias add + store ----
  // D layout (m89-verified): col = lane&15 (n), row = (lane>>4)*4 + reg (m)
#pragma unroll
  for (int ni = 0; ni < 4; ++ni) {
    int nloc = nloc0 + wc * 64 + ni * 16 + fr;
    float bv = bias_e[nloc];
#pragma unroll
    for (int mi = 0; mi < 4; ++mi) {
      int m = grow0 + wr * 64 + mi * 16 + fq * 4;
#pragma unroll
      for (int j = 0; j < 4; ++j) {
        float val = acc[mi][ni][j] + bv;
        if constexpr (OUT_BF16) {
          ((unsigned short*)Cv)[(size_t)(m + j) * N_ + nloc] = f2bf(val);
        } else {
          ((float*)Cv)[(size_t)(m + j) * N_ + nloc] = val;
        }
      }
    }
  }
}

extern "C" void kernel_launch(void* const* d_in, const int* in_sizes, int n_in,
                              void* d_out, int out_size, void* d_ws, size_t ws_size,
                              hipStream_t stream) {
  const float* x  = (const float*)d_in[0];   // (12288, 1024)
  const float* w1 = (const float*)d_in[1];   // (8, 4096, 1024)
  const float* b1 = (const float*)d_in[2];   // (8, 4096)
  const float* w2 = (const float*)d_in[3];   // (8, 1024, 4096)
  const float* b2 = (const float*)d_in[4];   // (8, 1024)
  // d_in[5] capacities: baked in at compile time

  unsigned short* H = (unsigned short*)d_ws;  // (12288, 4096) bf16 = 100 MB

  // GEMM1: H = X @ w1^T + b1   (K=1024, N=4096)
  gemm_expert<1024, 4096, 32, false, true>
      <<<96 * 32, 256, 0, stream>>>(x, w1, b1, H);
  // GEMM2: OUT = H @ w2^T + b2 (K=4096, N=1024)
  gemm_expert<4096, 1024, 8, true, false>
      <<<96 * 8, 256, 0, stream>>>(H, w2, b2, (float*)d_out);
}

// Round 2
// 250.674 us; speedup vs baseline: 1.8332x; 1.8332x over previous
//
#include <hip/hip_runtime.h>
#include <hip/hip_bf16.h>

#define DEV __device__ __forceinline__

typedef __bf16 bf16x8 __attribute__((ext_vector_type(8)));
typedef float  f32x4  __attribute__((ext_vector_type(4)));

// caps = {512,1024,2048,4096,1024,512,2048,1024}; 128-row-tile cumsum:
// {0,4,12,28,60,68,72,88,96}

DEV unsigned short f2bf(float f) {
  union { float f; unsigned u; } v; v.f = f;
  unsigned u = v.u;
  return (unsigned short)((u + 0x7FFFu + ((u >> 16) & 1u)) >> 16);  // RNE
}

// XOR swizzle inside an 8KB [128 rows][64 bytes] tile: involution, flips addr
// bits [6:4] by (row>>1)&7. Preserves 16B alignment -> conflict-free b128 reads.
DEV int swz(int r, int cbyte) {
  return (r * 64 + cbyte) ^ (((r >> 1) & 7) << 4);
}

DEV void gld_lds16(const void* g, void* l) {
  __builtin_amdgcn_global_load_lds(
      (const __attribute__((address_space(1))) unsigned int*)g,
      (__attribute__((address_space(3))) unsigned int*)l, 16, 0, 0);
}

// C = A @ B^T (+ bias). A: (Mtot x K_) contiguous, B: (E x N_ x K_) per-expert.
// AMODE/BMODE: 0 = f32 global, reg-staged + cvt into swizzled LDS
//              1 = bf16 global, global_load_lds w/ pre-swizzled source (m173)
template <int K_, int N_, int NCT_, int AMODE, int BMODE, bool OUT_BF16,
          bool HAS_BIAS, int EDIV>
__global__ __launch_bounds__(256)
void gemm_expert(const void* __restrict__ Av, const void* __restrict__ Bv,
                 const float* __restrict__ bias, void* __restrict__ Cv) {
  __shared__ char lds[16384];
  char* As = lds;
  char* Bs = lds + 8192;

  const int t    = threadIdx.x;
  const int lane = t & 63;
  const int wv   = t >> 6;
  const int wr   = wv >> 1;
  const int wc   = wv & 1;
  const int fr   = lane & 15;
  const int fq   = lane >> 4;

  const int rt = blockIdx.x / NCT_;
  const int ct = blockIdx.x - rt * NCT_;

  int e;
  if constexpr (EDIV > 0) {
    e = rt / EDIV;
  } else {
    const int cums[9] = {0, 4, 12, 28, 60, 68, 72, 88, 96};
    e = 0;
#pragma unroll
    for (int i = 1; i < 8; ++i) e += (rt >= cums[i]) ? 1 : 0;
  }

  const int grow0 = rt * 128;
  const int nloc0 = ct * 128;

  f32x4 acc[4][4];
#pragma unroll
  for (int i = 0; i < 4; ++i)
#pragma unroll
    for (int j = 0; j < 4; ++j) acc[i][j] = (f32x4){0.f, 0.f, 0.f, 0.f};

  for (int kb = 0; kb < K_; kb += 32) {
    __syncthreads();
    // ---- async bf16 staging (swizzled-source so LDS ends up swz-laid) ----
    if constexpr (AMODE == 1) {
      const unsigned short* Ab = (const unsigned short*)Av;
#pragma unroll
      for (int s = 0; s < 2; ++s) {
        int o = (wv * 2 + s) * 1024 + lane * 16;
        int p = o ^ (((o >> 7) & 7) << 4);
        const unsigned short* g =
            Ab + (size_t)(grow0 + (p >> 6)) * K_ + kb + ((p & 63) >> 1);
        gld_lds16(g, As + (wv * 2 + s) * 1024);
      }
    }
    if constexpr (BMODE == 1) {
      const unsigned short* Bb = (const unsigned short*)Bv + (size_t)e * N_ * K_;
#pragma unroll
      for (int s = 0; s < 2; ++s) {
        int o = (wv * 2 + s) * 1024 + lane * 16;
        int p = o ^ (((o >> 7) & 7) << 4);
        const unsigned short* g =
            Bb + (size_t)(nloc0 + (p >> 6)) * K_ + kb + ((p & 63) >> 1);
        gld_lds16(g, Bs + (wv * 2 + s) * 1024);
      }
    }
    // ---- f32 reg-staged + cvt sides ----
    if constexpr (AMODE == 0) {
      const float* Af = (const float*)Av;
#pragma unroll
      for (int it = 0; it < 4; ++it) {
        int q = t + it * 256, r = q >> 3, c = (q & 7) * 4;
        float4 f = *(const float4*)(Af + (size_t)(grow0 + r) * K_ + kb + c);
        ushort4 v = {f2bf(f.x), f2bf(f.y), f2bf(f.z), f2bf(f.w)};
        *(ushort4*)(As + swz(r, c * 2)) = v;
      }
    }
    if constexpr (BMODE == 0) {
      const float* Bf = (const float*)Bv + (size_t)e * N_ * K_;
#pragma unroll
      for (int it = 0; it < 4; ++it) {
        int q = t + it * 256, r = q >> 3, c = (q & 7) * 4;
        float4 f = *(const float4*)(Bf + (size_t)(nloc0 + r) * K_ + kb + c);
        ushort4 v = {f2bf(f.x), f2bf(f.y), f2bf(f.z), f2bf(f.w)};
        *(ushort4*)(Bs + swz(r, c * 2)) = v;
      }
    }
    __syncthreads();

    bf16x8 af[4], bfg[4];
#pragma unroll
    for (int mi = 0; mi < 4; ++mi)
      af[mi] = *(bf16x8*)(As + swz(wr * 64 + mi * 16 + fr, fq * 16));
#pragma unroll
    for (int ni = 0; ni < 4; ++ni)
      bfg[ni] = *(bf16x8*)(Bs + swz(wc * 64 + ni * 16 + fr, fq * 16));
#pragma unroll
    for (int mi = 0; mi < 4; ++mi)
#pragma unroll
      for (int ni = 0; ni < 4; ++ni)
        acc[mi][ni] = __builtin_amdgcn_mfma_f32_16x16x32_bf16(
            af[mi], bfg[ni], acc[mi][ni], 0, 0, 0);
  }

  // epilogue: D layout col=lane&15, row=(lane>>4)*4+reg (m89-verified)
#pragma unroll
  for (int ni = 0; ni < 4; ++ni) {
    int nloc = nloc0 + wc * 64 + ni * 16 + fr;
    float bv = 0.f;
    if constexpr (HAS_BIAS) bv = (bias + (size_t)e * N_)[nloc];
#pragma unroll
    for (int mi = 0; mi < 4; ++mi) {
      int m = grow0 + wr * 64 + mi * 16 + fq * 4;
#pragma unroll
      for (int j = 0; j < 4; ++j) {
        float val = acc[mi][ni][j] + bv;
        if constexpr (OUT_BF16)
          ((unsigned short*)Cv)[(size_t)(m + j) * N_ + nloc] = f2bf(val);
        else
          ((float*)Cv)[(size_t)(m + j) * N_ + nloc] = val;
      }
    }
  }
}

// w1 (E,4096,1024) f32 -> w1t (E,1024,4096) bf16, 64x64 tiles via LDS
__global__ __launch_bounds__(256)
void transpose_w1(const float* __restrict__ w1, unsigned short* __restrict__ w1t) {
  __shared__ unsigned short tl[64 * 68];
  int b = blockIdx.x;
  int jt = b & 15, kt = (b >> 4) & 63, e = b >> 10;
  const float* src = w1 + ((size_t)e * 4096 + kt * 64) * 1024 + jt * 64;
  int t = threadIdx.x;
#pragma unroll
  for (int it = 0; it < 4; ++it) {
    int q = t + it * 256, kr = q >> 4, jc = (q & 15) * 4;
    float4 f = *(const float4*)(src + (size_t)kr * 1024 + jc);
    ushort4 v = {f2bf(f.x), f2bf(f.y), f2bf(f.z), f2bf(f.w)};
    *(ushort4*)&tl[kr * 68 + jc] = v;
  }
  __syncthreads();
  unsigned short* dst = w1t + ((size_t)e * 1024 + jt * 64) * 4096 + kt * 64;
#pragma unroll
  for (int it = 0; it < 4; ++it) {
    int q = t + it * 256, jr = q >> 4, kc = (q & 15) * 4;
    ushort4 v = {tl[(kc + 0) * 68 + jr], tl[(kc + 1) * 68 + jr],
                 tl[(kc + 2) * 68 + jr], tl[(kc + 3) * 68 + jr]};
    *(ushort4*)(dst + (size_t)jr * 4096 + kc) = v;
  }
}

// per-row (e*1024+i): optional w2->bf16 convert + bc[row] = w2[row]·b1[e] + b2[row]
template <bool STORE_BF>
__global__ __launch_bounds__(256)
void conv_w2_bias(const float* __restrict__ w2, const float* __restrict__ b1,
                  const float* __restrict__ b2, unsigned short* __restrict__ w2bf,
                  float* __restrict__ bc) {
  int row = blockIdx.x, e = row >> 10, t = threadIdx.x;
  const float* src = w2 + (size_t)row * 4096;
  const float* b1e = b1 + (size_t)e * 4096;
  float acc = 0.f;
#pragma unroll
  for (int it = 0; it < 4; ++it) {
    int c = (t + it * 256) * 4;
    float4 f = *(const float4*)(src + c);
    float4 g = *(const float4*)(b1e + c);
    acc += f.x * g.x + f.y * g.y + f.z * g.z + f.w * g.w;
    if constexpr (STORE_BF) {
      ushort4 v = {f2bf(f.x), f2bf(f.y), f2bf(f.z), f2bf(f.w)};
      *(ushort4*)(w2bf + (size_t)row * 4096 + c) = v;
    }
  }
#pragma unroll
  for (int o = 32; o > 0; o >>= 1) acc += __shfl_down(acc, o);
  __shared__ float red[4];
  if ((t & 63) == 0) red[t >> 6] = acc;
  __syncthreads();
  if (t == 0) bc[row] = red[0] + red[1] + red[2] + red[3] + b2[row];
}

__global__ __launch_bounds__(256)
void conv_f32_bf16(const float* __restrict__ in, unsigned short* __restrict__ out,
                   int n4) {
  for (int i = blockIdx.x * 256 + threadIdx.x; i < n4; i += gridDim.x * 256) {
    float4 f = *(const float4*)(in + (size_t)i * 4);
    ushort4 v = {f2bf(f.x), f2bf(f.y), f2bf(f.z), f2bf(f.w)};
    *(ushort4*)(out + (size_t)i * 4) = v;
  }
}

extern "C" void kernel_launch(void* const* d_in, const int* in_sizes, int n_in,
                              void* d_out, int out_size, void* d_ws, size_t ws_size,
                              hipStream_t stream) {
  const float* x  = (const float*)d_in[0];   // (12288, 1024)
  const float* w1 = (const float*)d_in[1];   // (8, 4096, 1024)
  const float* b1 = (const float*)d_in[2];   // (8, 4096)
  const float* w2 = (const float*)d_in[3];   // (8, 1024, 4096)
  const float* b2 = (const float*)d_in[4];   // (8, 1024)

  char* ws = (char*)d_ws;
  unsigned short* w1t = (unsigned short*)ws;              // 64 MiB
  const size_t NEED_T2 = 151126016, NEED_T3 = 176291840;

  if (ws_size >= NEED_T2) {
    unsigned short* w2bf = (unsigned short*)(ws + 67108864);   // 64 MiB
    unsigned short* Wc   = (unsigned short*)(ws + 134217728);  // 16 MiB
    float*          bc   = (float*)(ws + 150994944);           // 32 KiB

    transpose_w1<<<8192, 256, 0, stream>>>(w1, w1t);
    conv_w2_bias<true><<<8192, 256, 0, stream>>>(w2, b1, b2, w2bf, bc);
    // Wc[e] = w2[e] @ w1t[e]^T : M=8192, N=1024, K=4096, all-bf16
    gemm_expert<4096, 1024, 8, 1, 1, true, false, 8>
        <<<512, 256, 0, stream>>>(w2bf, w1t, nullptr, Wc);
    if (ws_size >= NEED_T3) {
      unsigned short* xbf = (unsigned short*)(ws + 151126016);
      conv_f32_bf16<<<2048, 256, 0, stream>>>(x, xbf, 12288 * 1024 / 4);
      gemm_expert<1024, 1024, 8, 1, 1, false, true, 0>
          <<<768, 256, 0, stream>>>(xbf, Wc, bc, d_out);
    } else {
      gemm_expert<1024, 1024, 8, 0, 1, false, true, 0>
          <<<768, 256, 0, stream>>>(x, Wc, bc, d_out);
    }
  } else {
    // P2 fallback: no w2bf materialization (84 MiB ws)
    unsigned short* Wc = (unsigned short*)(ws + 67108864);
    float*          bc = (float*)(ws + 83886080);

    transpose_w1<<<8192, 256, 0, stream>>>(w1, w1t);
    conv_w2_bias<false><<<8192, 256, 0, stream>>>(w2, b1, b2, nullptr, bc);
    gemm_expert<4096, 1024, 8, 0, 1, true, false, 8>
        <<<512, 256, 0, stream>>>(w2, w1t, nullptr, Wc);
    gemm_expert<1024, 1024, 8, 0, 1, false, true, 0>
        <<<768, 256, 0, stream>>>(x, Wc, bc, d_out);
  }
}

// Round 3
// 239.983 us; speedup vs baseline: 1.9148x; 1.0445x over previous
//
#include <hip/hip_runtime.h>
#include <hip/hip_bf16.h>

#define DEV __device__ __forceinline__

typedef __bf16 bf16x8 __attribute__((ext_vector_type(8)));
typedef float  f32x4  __attribute__((ext_vector_type(4)));

// caps = {512,1024,2048,4096,1024,512,2048,1024}; 128-row-tile cumsum:
// {0,4,12,28,60,68,72,88,96}

DEV unsigned short f2bf(float f) {
  union { float f; unsigned u; } v; v.f = f;
  unsigned u = v.u;
  return (unsigned short)((u + 0x7FFFu + ((u >> 16) & 1u)) >> 16);  // RNE
}

// XOR swizzle inside a [rows][64-byte] LDS tile: flips addr bits [6:4] by
// (row>>1)&7. Involution, keeps 16B alignment -> conflict-free b128 reads.
DEV int swz(int r, int cbyte) {
  return (r * 64 + cbyte) ^ (((r >> 1) & 7) << 4);
}

DEV void gld_lds16(const void* g, void* l) {
  __builtin_amdgcn_global_load_lds(
      (const __attribute__((address_space(1))) unsigned int*)g,
      (__attribute__((address_space(3))) unsigned int*)l, 16, 0, 0);
}

// C = A @ B^T (+ bias). A: (Mtot x K_), B: (E x N_ x K_). Tile 128x64, BK=32,
// double-buffered LDS, 2-phase pipeline (stage t+1 before compute t, one
// barrier per K-step), XCD-bijective block swizzle.
// AMODE/BMODE: 0 = f32 global reg-staged+cvt; 1 = bf16 global_load_lds
// with pre-swizzled source (m173 pattern).
template <int K_, int N_, int NCT_, int AMODE, int BMODE, bool OUT_BF16,
          bool HAS_BIAS, int EDIV>
__global__ __launch_bounds__(256)
void gemm_expert(const void* __restrict__ Av, const void* __restrict__ Bv,
                 const float* __restrict__ bias, void* __restrict__ Cv) {
  // per buffer: A 128x32 bf16 = 8KB, B 64x32 bf16 = 4KB
  __shared__ char lds[2][12288];

  const int t    = threadIdx.x;
  const int lane = t & 63;
  const int wv   = t >> 6;
  const int wr   = wv >> 1;      // wave row 0..1 (64 rows each)
  const int wc   = wv & 1;       // wave col 0..1 (32 cols each)
  const int fr   = lane & 15;
  const int fq   = lane >> 4;

  // XCD-aware bijective swizzle (grids are multiples of 8)
  int bid = blockIdx.x;
  const int nwg = gridDim.x;
  if ((nwg & 7) == 0) bid = (bid & 7) * (nwg >> 3) + (bid >> 3);

  const int rt = bid / NCT_;
  const int ct = bid - rt * NCT_;

  int e;
  if constexpr (EDIV > 0) {
    e = rt / EDIV;
  } else {
    const int cums[9] = {0, 4, 12, 28, 60, 68, 72, 88, 96};
    e = 0;
#pragma unroll
    for (int i = 1; i < 8; ++i) e += (rt >= cums[i]) ? 1 : 0;
  }

  const int grow0 = rt * 128;
  const int nloc0 = ct * 64;

  f32x4 acc[4][2];
#pragma unroll
  for (int i = 0; i < 4; ++i)
#pragma unroll
    for (int j = 0; j < 2; ++j) acc[i][j] = (f32x4){0.f, 0.f, 0.f, 0.f};

  const unsigned short* Ab = (const unsigned short*)Av;
  const float*          Af = (const float*)Av;
  const unsigned short* Bb = (const unsigned short*)Bv + (size_t)e * N_ * K_;
  const float*          Bf = (const float*)Bv + (size_t)e * N_ * K_;

  auto stage = [&](int buf, int kb) {
    char* As = lds[buf];
    char* Bs = lds[buf] + 8192;
    if constexpr (AMODE == 1) {
#pragma unroll
      for (int s = 0; s < 2; ++s) {
        int o = (wv * 2 + s) * 1024 + lane * 16;
        int p = o ^ (((o >> 7) & 7) << 4);
        gld_lds16(Ab + (size_t)(grow0 + (p >> 6)) * K_ + kb + ((p & 63) >> 1),
                  As + (wv * 2 + s) * 1024);
      }
    } else {
#pragma unroll
      for (int it = 0; it < 4; ++it) {
        int q = t + it * 256, r = q >> 3, c = (q & 7) * 4;
        float4 f = *(const float4*)(Af + (size_t)(grow0 + r) * K_ + kb + c);
        ushort4 v = {f2bf(f.x), f2bf(f.y), f2bf(f.z), f2bf(f.w)};
        *(ushort4*)(As + swz(r, c * 2)) = v;
      }
    }
    if constexpr (BMODE == 1) {
      int o = wv * 1024 + lane * 16;
      int p = o ^ (((o >> 7) & 7) << 4);
      gld_lds16(Bb + (size_t)(nloc0 + (p >> 6)) * K_ + kb + ((p & 63) >> 1),
                Bs + wv * 1024);
    } else {
#pragma unroll
      for (int it = 0; it < 2; ++it) {
        int q = t + it * 256, r = q >> 3, c = (q & 7) * 4;
        float4 f = *(const float4*)(Bf + (size_t)(nloc0 + r) * K_ + kb + c);
        ushort4 v = {f2bf(f.x), f2bf(f.y), f2bf(f.z), f2bf(f.w)};
        *(ushort4*)(Bs + swz(r, c * 2)) = v;
      }
    }
  };

  auto compute = [&](int buf) {
    char* As = lds[buf];
    char* Bs = lds[buf] + 8192;
    bf16x8 af[4], bfg[2];
#pragma unroll
    for (int mi = 0; mi < 4; ++mi)
      af[mi] = *(bf16x8*)(As + swz(wr * 64 + mi * 16 + fr, fq * 16));
#pragma unroll
    for (int ni = 0; ni < 2; ++ni)
      bfg[ni] = *(bf16x8*)(Bs + swz(wc * 32 + ni * 16 + fr, fq * 16));
#pragma unroll
    for (int mi = 0; mi < 4; ++mi)
#pragma unroll
      for (int ni = 0; ni < 2; ++ni)
        acc[mi][ni] = __builtin_amdgcn_mfma_f32_16x16x32_bf16(
            af[mi], bfg[ni], acc[mi][ni], 0, 0, 0);
  };

  int cur = 0;
  stage(0, 0);
  __syncthreads();
#pragma unroll 2
  for (int kb = 32; kb < K_; kb += 32) {
    stage(cur ^ 1, kb);   // prefetch next tile (latency hidden under compute)
    compute(cur);
    __syncthreads();      // drains vmcnt+lgkm; next buffer ready
    cur ^= 1;
  }
  compute(cur);

  // epilogue: D layout col=lane&15, row=(lane>>4)*4+reg (m89-verified)
#pragma unroll
  for (int ni = 0; ni < 2; ++ni) {
    int nloc = nloc0 + wc * 32 + ni * 16 + fr;
    float bv = 0.f;
    if constexpr (HAS_BIAS) bv = (bias + (size_t)e * N_)[nloc];
#pragma unroll
    for (int mi = 0; mi < 4; ++mi) {
      int m = grow0 + wr * 64 + mi * 16 + fq * 4;
#pragma unroll
      for (int j = 0; j < 4; ++j) {
        float val = acc[mi][ni][j] + bv;
        if constexpr (OUT_BF16)
          ((unsigned short*)Cv)[(size_t)(m + j) * N_ + nloc] = f2bf(val);
        else
          ((float*)Cv)[(size_t)(m + j) * N_ + nloc] = val;
      }
    }
  }
}

// w1 (E,4096,1024) f32 -> w1t (E,1024,4096) bf16, 64x64 tiles via LDS
__global__ __launch_bounds__(256)
void transpose_w1(const float* __restrict__ w1, unsigned short* __restrict__ w1t) {
  __shared__ unsigned short tl[64 * 68];
  int b = blockIdx.x;
  int jt = b & 15, kt = (b >> 4) & 63, e = b >> 10;
  const float* src = w1 + ((size_t)e * 4096 + kt * 64) * 1024 + jt * 64;
  int t = threadIdx.x;
#pragma unroll
  for (int it = 0; it < 4; ++it) {
    int q = t + it * 256, kr = q >> 4, jc = (q & 15) * 4;
    float4 f = *(const float4*)(src + (size_t)kr * 1024 + jc);
    ushort4 v = {f2bf(f.x), f2bf(f.y), f2bf(f.z), f2bf(f.w)};
    *(ushort4*)&tl[kr * 68 + jc] = v;
  }
  __syncthreads();
  unsigned short* dst = w1t + ((size_t)e * 1024 + jt * 64) * 4096 + kt * 64;
#pragma unroll
  for (int it = 0; it < 4; ++it) {
    int q = t + it * 256, jr = q >> 4, kc = (q & 15) * 4;
    ushort4 v = {tl[(kc + 0) * 68 + jr], tl[(kc + 1) * 68 + jr],
                 tl[(kc + 2) * 68 + jr], tl[(kc + 3) * 68 + jr]};
    *(ushort4*)(dst + (size_t)jr * 4096 + kc) = v;
  }
}

// per-row (e*1024+i): optional w2->bf16 convert + bc[row] = w2[row]·b1[e] + b2[row]
template <bool STORE_BF>
__global__ __launch_bounds__(256)
void conv_w2_bias(const float* __restrict__ w2, const float* __restrict__ b1,
                  const float* __restrict__ b2, unsigned short* __restrict__ w2bf,
                  float* __restrict__ bc) {
  int row = blockIdx.x, e = row >> 10, t = threadIdx.x;
  const float* src = w2 + (size_t)row * 4096;
  const float* b1e = b1 + (size_t)e * 4096;
  float acc = 0.f;
#pragma unroll
  for (int it = 0; it < 4; ++it) {
    int c = (t + it * 256) * 4;
    float4 f = *(const float4*)(src + c);
    float4 g = *(const float4*)(b1e + c);
    acc += f.x * g.x + f.y * g.y + f.z * g.z + f.w * g.w;
    if constexpr (STORE_BF) {
      ushort4 v = {f2bf(f.x), f2bf(f.y), f2bf(f.z), f2bf(f.w)};
      *(ushort4*)(w2bf + (size_t)row * 4096 + c) = v;
    }
  }
#pragma unroll
  for (int o = 32; o > 0; o >>= 1) acc += __shfl_down(acc, o);
  __shared__ float red[4];
  if ((t & 63) == 0) red[t >> 6] = acc;
  __syncthreads();
  if (t == 0) bc[row] = red[0] + red[1] + red[2] + red[3] + b2[row];
}

__global__ __launch_bounds__(256)
void conv_f32_bf16(const float* __restrict__ in, unsigned short* __restrict__ out,
                   int n4) {
  for (int i = blockIdx.x * 256 + threadIdx.x; i < n4; i += gridDim.x * 256) {
    float4 f = *(const float4*)(in + (size_t)i * 4);
    ushort4 v = {f2bf(f.x), f2bf(f.y), f2bf(f.z), f2bf(f.w)};
    *(ushort4*)(out + (size_t)i * 4) = v;
  }
}

extern "C" void kernel_launch(void* const* d_in, const int* in_sizes, int n_in,
                              void* d_out, int out_size, void* d_ws, size_t ws_size,
                              hipStream_t stream) {
  const float* x  = (const float*)d_in[0];   // (12288, 1024)
  const float* w1 = (const float*)d_in[1];   // (8, 4096, 1024)
  const float* b1 = (const float*)d_in[2];   // (8, 4096)
  const float* w2 = (const float*)d_in[3];   // (8, 1024, 4096)
  const float* b2 = (const float*)d_in[4];   // (8, 1024)

  char* ws = (char*)d_ws;
  unsigned short* w1t = (unsigned short*)ws;              // 64 MiB
  const size_t NEED_T2 = 151126016, NEED_T3 = 176291840;

  if (ws_size >= NEED_T2) {
    unsigned short* w2bf = (unsigned short*)(ws + 67108864);   // 64 MiB
    unsigned short* Wc   = (unsigned short*)(ws + 134217728);  // 16 MiB
    float*          bc   = (float*)(ws + 150994944);           // 32 KiB

    transpose_w1<<<8192, 256, 0, stream>>>(w1, w1t);
    conv_w2_bias<true><<<8192, 256, 0, stream>>>(w2, b1, b2, w2bf, bc);
    // Wc[e] = w2bf[e] @ w1t[e]^T : M=8192, N=1024, K=4096
    gemm_expert<4096, 1024, 16, 1, 1, true, false, 8>
        <<<1024, 256, 0, stream>>>(w2bf, w1t, nullptr, Wc);
    if (ws_size >= NEED_T3) {
      unsigned short* xbf = (unsigned short*)(ws + 151126016);
      conv_f32_bf16<<<2048, 256, 0, stream>>>(x, xbf, 12288 * 1024 / 4);
      gemm_expert<1024, 1024, 16, 1, 1, false, true, 0>
          <<<1536, 256, 0, stream>>>(xbf, Wc, bc, d_out);
    } else {
      gemm_expert<1024, 1024, 16, 0, 1, false, true, 0>
          <<<1536, 256, 0, stream>>>(x, Wc, bc, d_out);
    }
  } else {
    // P2 fallback: no w2bf materialization (84 MiB ws)
    unsigned short* Wc = (unsigned short*)(ws + 67108864);
    float*          bc = (float*)(ws + 83886080);

    transpose_w1<<<8192, 256, 0, stream>>>(w1, w1t);
    conv_w2_bias<false><<<8192, 256, 0, stream>>>(w2, b1, b2, nullptr, bc);
    gemm_expert<4096, 1024, 16, 0, 1, true, false, 8>
        <<<1024, 256, 0, stream>>>(w2, w1t, nullptr, Wc);
    gemm_expert<1024, 1024, 16, 0, 1, false, true, 0>
        <<<1536, 256, 0, stream>>>(x, Wc, bc, d_out);
  }
}

// Round 4
// 204.670 us; speedup vs baseline: 2.2452x; 1.1725x over previous
//
#include <hip/hip_runtime.h>
#include <hip/hip_bf16.h>

#define DEV __device__ __forceinline__

typedef __bf16 bf16x8 __attribute__((ext_vector_type(8)));
typedef float  f32x4  __attribute__((ext_vector_type(4)));

// caps = {512,1024,2048,4096,1024,512,2048,1024}
// 128-row-tile cumsum: {0,4,12,28,60,68,72,88,96}
// 256-row-tile cumsum: {0,2,6,14,30,34,36,44,48}

DEV unsigned short f2bf(float f) {
  union { float f; unsigned u; } v; v.f = f;
  unsigned u = v.u;
  return (unsigned short)((u + 0x7FFFu + ((u >> 16) & 1u)) >> 16);  // RNE
}

DEV void gld_lds16(const void* g, void* l) {
  __builtin_amdgcn_global_load_lds(
      (const __attribute__((address_space(1))) unsigned int*)g,
      (__attribute__((address_space(3))) unsigned int*)l, 16, 0, 0);
}

// ---------------------------------------------------------------------------
// 8-wave deep-pipeline GEMM: C = A @ B^T (+bias).  A:(Mtot x K_) bf16,
// B:(E x N_ x K_) bf16.  Tile 256x128, BK=64, 3-deep LDS ring (144KB,
// 1 block/CU), counted vmcnt (T4), setprio around MFMA (T5), XOR-swizzled
// LDS via pre-swizzled global source (m173 / rule 21).
// ---------------------------------------------------------------------------
template <int K_, int N_, bool OUT_BF16, bool HAS_BIAS, int EDIV>
__global__ __launch_bounds__(512, 2)
void gemm8(const unsigned short* __restrict__ A,
           const unsigned short* __restrict__ B,
           const float* __restrict__ bias, void* __restrict__ Cv) {
  // per buffer: A 256x64 bf16 = 32KB, B 128x64 bf16 = 16KB
  __shared__ __align__(128) char lds[3][49152];

  const int t    = threadIdx.x;
  const int lane = t & 63;
  const int wv   = t >> 6;
  const int wm   = wv >> 1;      // wave row 0..3 (64 out-rows each)
  const int wn   = wv & 1;       // wave col 0..1 (64 out-cols each)
  const int fr   = lane & 15;
  const int fq   = lane >> 4;

  constexpr int NCT = N_ / 128;
  constexpr int NT  = K_ / 64;

  // XCD-bijective swizzle (grids here are always multiples of 8)
  int bid = blockIdx.x;
  const int nwg = gridDim.x;
  bid = (bid & 7) * (nwg >> 3) + (bid >> 3);

  const int rt = bid / NCT;
  const int ct = bid - rt * NCT;

  int e;
  if constexpr (EDIV > 0) {
    e = rt / EDIV;
  } else {
    const int cums[9] = {0, 2, 6, 14, 30, 34, 36, 44, 48};
    e = 0;
#pragma unroll
    for (int i = 1; i < 8; ++i) e += (rt >= cums[i]) ? 1 : 0;
  }

  const int grow0 = rt * 256;
  const int nloc0 = ct * 128;
  const unsigned short* Bg = B + (size_t)e * N_ * K_;

  f32x4 acc[4][4];
#pragma unroll
  for (int i = 0; i < 4; ++i)
#pragma unroll
    for (int j = 0; j < 4; ++j) acc[i][j] = (f32x4){0.f, 0.f, 0.f, 0.f};

  // stage one K-tile (6 gld_lds16/thread). LDS dest linear; source address
  // carries the inverse swizzle so reads can use cb ^= (row&7)<<4.
  auto stage = [&](int buf, int tk) {
    const int kb = tk * 64;
    char* Abase = lds[buf];
    char* Bbase = lds[buf] + 32768;
#pragma unroll
    for (int s = 0; s < 4; ++s) {
      int o  = s * 8192 + wv * 1024 + lane * 16;
      int r  = o >> 7;                          // A-tile row 0..255
      int cb = (o & 127) ^ ((r & 7) << 4);
      gld_lds16(A + (size_t)(grow0 + r) * K_ + kb + (cb >> 1),
                Abase + s * 8192 + wv * 1024);
    }
#pragma unroll
    for (int s = 0; s < 2; ++s) {
      int o  = s * 8192 + wv * 1024 + lane * 16;
      int r  = o >> 7;                          // B-tile row 0..127
      int cb = (o & 127) ^ ((r & 7) << 4);
      gld_lds16(Bg + (size_t)(nloc0 + r) * K_ + kb + (cb >> 1),
                Bbase + s * 8192 + wv * 1024);
    }
  };

  auto compute = [&](int buf) {
    char* Abase = lds[buf];
    char* Bbase = lds[buf] + 32768;
    bf16x8 af[4][2], bf[4][2];
#pragma unroll
    for (int mi = 0; mi < 4; ++mi) {
      int r = wm * 64 + mi * 16 + fr;
#pragma unroll
      for (int k = 0; k < 2; ++k) {
        int cb = (k * 64 + fq * 16) ^ ((r & 7) << 4);
        af[mi][k] = *(bf16x8*)(Abase + r * 128 + cb);
      }
    }
#pragma unroll
    for (int ni = 0; ni < 4; ++ni) {
      int r = wn * 64 + ni * 16 + fr;
#pragma unroll
      for (int k = 0; k < 2; ++k) {
        int cb = (k * 64 + fq * 16) ^ ((r & 7) << 4);
        bf[ni][k] = *(bf16x8*)(Bbase + r * 128 + cb);
      }
    }
    __builtin_amdgcn_s_setprio(1);
#pragma unroll
    for (int k = 0; k < 2; ++k)
#pragma unroll
      for (int mi = 0; mi < 4; ++mi)
#pragma unroll
        for (int ni = 0; ni < 4; ++ni)
          acc[mi][ni] = __builtin_amdgcn_mfma_f32_16x16x32_bf16(
              af[mi][k], bf[ni][k], acc[mi][ni], 0, 0, 0);
    __builtin_amdgcn_s_setprio(0);
  };

  stage(0, 0);
  stage(1, 1);
  int cur = 0;
  for (int tk = 0; tk < NT; ++tk) {
    if (tk + 2 < NT) {
      int nb = cur + 2; if (nb >= 3) nb -= 3;
      stage(nb, tk + 2);
      asm volatile("s_waitcnt vmcnt(12)" ::: "memory");  // tile tk landed
    } else if (tk + 1 < NT) {
      asm volatile("s_waitcnt vmcnt(6)" ::: "memory");
    } else {
      asm volatile("s_waitcnt vmcnt(0)" ::: "memory");
    }
    __builtin_amdgcn_s_barrier();            // all waves' tile tk in LDS
    __builtin_amdgcn_sched_barrier(0);
    compute(cur);
    __builtin_amdgcn_sched_barrier(0);
    asm volatile("s_waitcnt lgkmcnt(0)" ::: "memory");   // ds_reads drained
    __builtin_amdgcn_sched_barrier(0);
    __builtin_amdgcn_s_barrier();            // buf[cur] free to overwrite
    ++cur; if (cur >= 3) cur = 0;
  }

  // epilogue: D layout col=lane&15 (n), row=(lane>>4)*4+reg (m)  [m89]
#pragma unroll
  for (int ni = 0; ni < 4; ++ni) {
    int nloc = nloc0 + wn * 64 + ni * 16 + fr;
    float bv = 0.f;
    if constexpr (HAS_BIAS) bv = (bias + (size_t)e * N_)[nloc];
#pragma unroll
    for (int mi = 0; mi < 4; ++mi) {
      int m = grow0 + wm * 64 + mi * 16 + fq * 4;
#pragma unroll
      for (int j = 0; j < 4; ++j) {
        float val = acc[mi][ni][j] + bv;
        if constexpr (OUT_BF16)
          ((unsigned short*)Cv)[(size_t)(m + j) * N_ + nloc] = f2bf(val);
        else
          ((float*)Cv)[(size_t)(m + j) * N_ + nloc] = val;
      }
    }
  }
}

// ---------------------------------------------------------------------------
// Proven 2-phase 128x64 template — kept for low-ws fallback paths only.
// ---------------------------------------------------------------------------
DEV int swz(int r, int cbyte) {
  return (r * 64 + cbyte) ^ (((r >> 1) & 7) << 4);
}

template <int K_, int N_, int NCT_, int AMODE, int BMODE, bool OUT_BF16,
          bool HAS_BIAS, int EDIV>
__global__ __launch_bounds__(256)
void gemm_expert(const void* __restrict__ Av, const void* __restrict__ Bv,
                 const float* __restrict__ bias, void* __restrict__ Cv) {
  __shared__ char lds[2][12288];

  const int t    = threadIdx.x;
  const int lane = t & 63;
  const int wv   = t >> 6;
  const int wr   = wv >> 1;
  const int wc   = wv & 1;
  const int fr   = lane & 15;
  const int fq   = lane >> 4;

  int bid = blockIdx.x;
  const int nwg = gridDim.x;
  if ((nwg & 7) == 0) bid = (bid & 7) * (nwg >> 3) + (bid >> 3);

  const int rt = bid / NCT_;
  const int ct = bid - rt * NCT_;

  int e;
  if constexpr (EDIV > 0) {
    e = rt / EDIV;
  } else {
    const int cums[9] = {0, 4, 12, 28, 60, 68, 72, 88, 96};
    e = 0;
#pragma unroll
    for (int i = 1; i < 8; ++i) e += (rt >= cums[i]) ? 1 : 0;
  }

  const int grow0 = rt * 128;
  const int nloc0 = ct * 64;

  f32x4 acc[4][2];
#pragma unroll
  for (int i = 0; i < 4; ++i)
#pragma unroll
    for (int j = 0; j < 2; ++j) acc[i][j] = (f32x4){0.f, 0.f, 0.f, 0.f};

  const unsigned short* Ab = (const unsigned short*)Av;
  const float*          Af = (const float*)Av;
  const unsigned short* Bb = (const unsigned short*)Bv + (size_t)e * N_ * K_;
  const float*          Bf = (const float*)Bv + (size_t)e * N_ * K_;

  auto stage = [&](int buf, int kb) {
    char* As = lds[buf];
    char* Bs = lds[buf] + 8192;
    if constexpr (AMODE == 1) {
#pragma unroll
      for (int s = 0; s < 2; ++s) {
        int o = (wv * 2 + s) * 1024 + lane * 16;
        int p = o ^ (((o >> 7) & 7) << 4);
        gld_lds16(Ab + (size_t)(grow0 + (p >> 6)) * K_ + kb + ((p & 63) >> 1),
                  As + (wv * 2 + s) * 1024);
      }
    } else {
#pragma unroll
      for (int it = 0; it < 4; ++it) {
        int q = t + it * 256, r = q >> 3, c = (q & 7) * 4;
        float4 f = *(const float4*)(Af + (size_t)(grow0 + r) * K_ + kb + c);
        ushort4 v = {f2bf(f.x), f2bf(f.y), f2bf(f.z), f2bf(f.w)};
        *(ushort4*)(As + swz(r, c * 2)) = v;
      }
    }
    if constexpr (BMODE == 1) {
      int o = wv * 1024 + lane * 16;
      int p = o ^ (((o >> 7) & 7) << 4);
      gld_lds16(Bb + (size_t)(nloc0 + (p >> 6)) * K_ + kb + ((p & 63) >> 1),
                Bs + wv * 1024);
    } else {
#pragma unroll
      for (int it = 0; it < 2; ++it) {
        int q = t + it * 256, r = q >> 3, c = (q & 7) * 4;
        float4 f = *(const float4*)(Bf + (size_t)(nloc0 + r) * K_ + kb + c);
        ushort4 v = {f2bf(f.x), f2bf(f.y), f2bf(f.z), f2bf(f.w)};
        *(ushort4*)(Bs + swz(r, c * 2)) = v;
      }
    }
  };

  auto compute = [&](int buf) {
    char* As = lds[buf];
    char* Bs = lds[buf] + 8192;
    bf16x8 af[4], bfg[2];
#pragma unroll
    for (int mi = 0; mi < 4; ++mi)
      af[mi] = *(bf16x8*)(As + swz(wr * 64 + mi * 16 + fr, fq * 16));
#pragma unroll
    for (int ni = 0; ni < 2; ++ni)
      bfg[ni] = *(bf16x8*)(Bs + swz(wc * 32 + ni * 16 + fr, fq * 16));
#pragma unroll
    for (int mi = 0; mi < 4; ++mi)
#pragma unroll
      for (int ni = 0; ni < 2; ++ni)
        acc[mi][ni] = __builtin_amdgcn_mfma_f32_16x16x32_bf16(
            af[mi], bfg[ni], acc[mi][ni], 0, 0, 0);
  };

  int cur = 0;
  stage(0, 0);
  __syncthreads();
#pragma unroll 2
  for (int kb = 32; kb < K_; kb += 32) {
    stage(cur ^ 1, kb);
    compute(cur);
    __syncthreads();
    cur ^= 1;
  }
  compute(cur);

#pragma unroll
  for (int ni = 0; ni < 2; ++ni) {
    int nloc = nloc0 + wc * 32 + ni * 16 + fr;
    float bv = 0.f;
    if constexpr (HAS_BIAS) bv = (bias + (size_t)e * N_)[nloc];
#pragma unroll
    for (int mi = 0; mi < 4; ++mi) {
      int m = grow0 + wr * 64 + mi * 16 + fq * 4;
#pragma unroll
      for (int j = 0; j < 4; ++j) {
        float val = acc[mi][ni][j] + bv;
        if constexpr (OUT_BF16)
          ((unsigned short*)Cv)[(size_t)(m + j) * N_ + nloc] = f2bf(val);
        else
          ((float*)Cv)[(size_t)(m + j) * N_ + nloc] = val;
      }
    }
  }
}

// w1 (E,4096,1024) f32 -> w1t (E,1024,4096) bf16, 64x64 tiles via LDS
__global__ __launch_bounds__(256)
void transpose_w1(const float* __restrict__ w1, unsigned short* __restrict__ w1t) {
  __shared__ unsigned short tl[64 * 68];
  int b = blockIdx.x;
  int jt = b & 15, kt = (b >> 4) & 63, e = b >> 10;
  const float* src = w1 + ((size_t)e * 4096 + kt * 64) * 1024 + jt * 64;
  int t = threadIdx.x;
#pragma unroll
  for (int it = 0; it < 4; ++it) {
    int q = t + it * 256, kr = q >> 4, jc = (q & 15) * 4;
    float4 f = *(const float4*)(src + (size_t)kr * 1024 + jc);
    ushort4 v = {f2bf(f.x), f2bf(f.y), f2bf(f.z), f2bf(f.w)};
    *(ushort4*)&tl[kr * 68 + jc] = v;
  }
  __syncthreads();
  unsigned short* dst = w1t + ((size_t)e * 1024 + jt * 64) * 4096 + kt * 64;
#pragma unroll
  for (int it = 0; it < 4; ++it) {
    int q = t + it * 256, jr = q >> 4, kc = (q & 15) * 4;
    ushort4 v = {tl[(kc + 0) * 68 + jr], tl[(kc + 1) * 68 + jr],
                 tl[(kc + 2) * 68 + jr], tl[(kc + 3) * 68 + jr]};
    *(ushort4*)(dst + (size_t)jr * 4096 + kc) = v;
  }
}

// per-row (e*1024+i): optional w2->bf16 convert + bc[row] = w2[row]·b1[e] + b2[row]
template <bool STORE_BF>
__global__ __launch_bounds__(256)
void conv_w2_bias(const float* __restrict__ w2, const float* __restrict__ b1,
                  const float* __restrict__ b2, unsigned short* __restrict__ w2bf,
                  float* __restrict__ bc) {
  int row = blockIdx.x, e = row >> 10, t = threadIdx.x;
  const float* src = w2 + (size_t)row * 4096;
  const float* b1e = b1 + (size_t)e * 4096;
  float acc = 0.f;
#pragma unroll
  for (int it = 0; it < 4; ++it) {
    int c = (t + it * 256) * 4;
    float4 f = *(const float4*)(src + c);
    float4 g = *(const float4*)(b1e + c);
    acc += f.x * g.x + f.y * g.y + f.z * g.z + f.w * g.w;
    if constexpr (STORE_BF) {
      ushort4 v = {f2bf(f.x), f2bf(f.y), f2bf(f.z), f2bf(f.w)};
      *(ushort4*)(w2bf + (size_t)row * 4096 + c) = v;
    }
  }
#pragma unroll
  for (int o = 32; o > 0; o >>= 1) acc += __shfl_down(acc, o);
  __shared__ float red[4];
  if ((t & 63) == 0) red[t >> 6] = acc;
  __syncthreads();
  if (t == 0) bc[row] = red[0] + red[1] + red[2] + red[3] + b2[row];
}

__global__ __launch_bounds__(256)
void conv_f32_bf16(const float* __restrict__ in, unsigned short* __restrict__ out,
                   int n4) {
  for (int i = blockIdx.x * 256 + threadIdx.x; i < n4; i += gridDim.x * 256) {
    float4 f = *(const float4*)(in + (size_t)i * 4);
    ushort4 v = {f2bf(f.x), f2bf(f.y), f2bf(f.z), f2bf(f.w)};
    *(ushort4*)(out + (size_t)i * 4) = v;
  }
}

extern "C" void kernel_launch(void* const* d_in, const int* in_sizes, int n_in,
                              void* d_out, int out_size, void* d_ws, size_t ws_size,
                              hipStream_t stream) {
  const float* x  = (const float*)d_in[0];   // (12288, 1024)
  const float* w1 = (const float*)d_in[1];   // (8, 4096, 1024)
  const float* b1 = (const float*)d_in[2];   // (8, 4096)
  const float* w2 = (const float*)d_in[3];   // (8, 1024, 4096)
  const float* b2 = (const float*)d_in[4];   // (8, 1024)

  char* ws = (char*)d_ws;
  unsigned short* w1t = (unsigned short*)ws;              // 64 MiB
  const size_t NEED_T2 = 151126016, NEED_T3 = 176291840;

  if (ws_size >= NEED_T2) {
    unsigned short* w2bf = (unsigned short*)(ws + 67108864);   // 64 MiB
    unsigned short* Wc   = (unsigned short*)(ws + 134217728);  // 16 MiB
    float*          bc   = (float*)(ws + 150994944);           // 32 KiB

    transpose_w1<<<8192, 256, 0, stream>>>(w1, w1t);
    conv_w2_bias<true><<<8192, 256, 0, stream>>>(w2, b1, b2, w2bf, bc);
    // Wc[e] = w2bf[e] @ w1t[e]^T : M=8192, N=1024, K=4096
    gemm8<4096, 1024, true, false, 4>
        <<<256, 512, 0, stream>>>(w2bf, w1t, nullptr, Wc);
    if (ws_size >= NEED_T3) {
      unsigned short* xbf = (unsigned short*)(ws + 151126016);
      conv_f32_bf16<<<2048, 256, 0, stream>>>(x, xbf, 12288 * 1024 / 4);
      gemm8<1024, 1024, false, true, 0>
          <<<384, 512, 0, stream>>>(xbf, Wc, bc, (float*)d_out);
    } else {
      gemm_expert<1024, 1024, 16, 0, 1, false, true, 0>
          <<<1536, 256, 0, stream>>>(x, Wc, bc, d_out);
    }
  } else {
    // P2 fallback: no w2bf materialization (84 MiB ws)
    unsigned short* Wc = (unsigned short*)(ws + 67108864);
    float*          bc = (float*)(ws + 83886080);

    transpose_w1<<<8192, 256, 0, stream>>>(w1, w1t);
    conv_w2_bias<false><<<8192, 256, 0, stream>>>(w2, b1, b2, nullptr, bc);
    gemm_expert<4096, 1024, 16, 0, 1, true, false, 8>
        <<<1024, 256, 0, stream>>>(w2, w1t, nullptr, Wc);
    gemm_expert<1024, 1024, 16, 0, 1, false, true, 0>
        <<<1536, 256, 0, stream>>>(x, Wc, bc, d_out);
  }
}

// Round 5
// 204.218 us; speedup vs baseline: 2.2502x; 1.0022x over previous
//
#include <hip/hip_runtime.h>
#include <hip/hip_bf16.h>

#define DEV __device__ __forceinline__

typedef __bf16 bf16x8 __attribute__((ext_vector_type(8)));
typedef float  f32x4  __attribute__((ext_vector_type(4)));

// caps = {512,1024,2048,4096,1024,512,2048,1024}
// 128-row-tile cumsum: {0,4,12,28,60,68,72,88,96}
// 256-row-tile cumsum: {0,2,6,14,30,34,36,44,48}

DEV unsigned short f2bf(float f) {
  union { float f; unsigned u; } v; v.f = f;
  unsigned u = v.u;
  return (unsigned short)((u + 0x7FFFu + ((u >> 16) & 1u)) >> 16);  // RNE
}

DEV void gld_lds16(const void* g, void* l) {
  __builtin_amdgcn_global_load_lds(
      (const __attribute__((address_space(1))) unsigned int*)g,
      (__attribute__((address_space(3))) unsigned int*)l, 16, 0, 0);
}

#define WAITVM(N) asm volatile("s_waitcnt vmcnt(" #N ")" ::: "memory"); \
                  __builtin_amdgcn_sched_barrier(0)
#define WAITLG(N) asm volatile("s_waitcnt lgkmcnt(" #N ")" ::: "memory"); \
                  __builtin_amdgcn_sched_barrier(0)

// ---------------------------------------------------------------------------
// 8-wave phase-interleaved GEMM: C = A @ B^T (+bias). A:(Mtot x K_) bf16,
// B:(E x N_ x K_) bf16. Tile 256x128 (waves 4x2, wave-tile 64x64), BK=64,
// double-buffered LDS (96KB), counted vmcnt (T4), 2-phase MFMA split with
// interleaved ds_read (T3/m196), setprio (T5), XOR-swizzled LDS via
// pre-swizzled global source (m173 / rule 21), XCD-bijective grid swizzle.
// ---------------------------------------------------------------------------
template <int K_, int N_, bool OUT_BF16, bool HAS_BIAS, int EDIV>
__global__ __launch_bounds__(512, 2)
void gemm8(const unsigned short* __restrict__ A,
           const unsigned short* __restrict__ B,
           const float* __restrict__ bias, void* __restrict__ Cv) {
  // per buffer: A 256x64 bf16 = 32KB, B 128x64 bf16 = 16KB
  __shared__ __align__(128) char lds[2][49152];

  const int t    = threadIdx.x;
  const int lane = t & 63;
  const int wv   = t >> 6;
  const int wm   = wv >> 1;      // wave row 0..3 (64 out-rows)
  const int wn   = wv & 1;       // wave col 0..1 (64 out-cols)
  const int fr   = lane & 15;
  const int fq   = lane >> 4;

  constexpr int NCT = N_ / 128;
  constexpr int NT  = K_ / 64;

  int bid = blockIdx.x;
  const int nwg = gridDim.x;
  bid = (bid & 7) * (nwg >> 3) + (bid >> 3);   // grids are multiples of 8

  const int rt = bid / NCT;
  const int ct = bid - rt * NCT;

  int e;
  if constexpr (EDIV > 0) {
    e = rt / EDIV;
  } else {
    const int cums[9] = {0, 2, 6, 14, 30, 34, 36, 44, 48};
    e = 0;
#pragma unroll
    for (int i = 1; i < 8; ++i) e += (rt >= cums[i]) ? 1 : 0;
  }

  const int grow0 = rt * 256;
  const int nloc0 = ct * 128;
  const unsigned short* Bg = B + (size_t)e * N_ * K_;

  f32x4 acc[4][4];
#pragma unroll
  for (int i = 0; i < 4; ++i)
#pragma unroll
    for (int j = 0; j < 4; ++j) acc[i][j] = (f32x4){0.f, 0.f, 0.f, 0.f};

  // 6 gld_lds16 per thread per K-tile. LDS dest linear; source carries the
  // inverse swizzle so reads use cb ^= (row&7)<<4.
  auto stage = [&](int buf, int tk) {
    const int kb = tk * 64;
    char* Abase = lds[buf];
    char* Bbase = lds[buf] + 32768;
#pragma unroll
    for (int s = 0; s < 4; ++s) {
      int o  = s * 8192 + wv * 1024 + lane * 16;
      int r  = o >> 7;
      int cb = (o & 127) ^ ((r & 7) << 4);
      gld_lds16(A + (size_t)(grow0 + r) * K_ + kb + (cb >> 1),
                Abase + s * 8192 + wv * 1024);
    }
#pragma unroll
    for (int s = 0; s < 2; ++s) {
      int o  = s * 8192 + wv * 1024 + lane * 16;
      int r  = o >> 7;
      int cb = (o & 127) ^ ((r & 7) << 4);
      gld_lds16(Bg + (size_t)(nloc0 + r) * K_ + kb + (cb >> 1),
                Bbase + s * 8192 + wv * 1024);
    }
  };

  stage(0, 0);
  for (int tk = 0; tk < NT; ++tk) {
    const int cur = tk & 1;
    if (tk + 1 < NT) {
      stage(cur ^ 1, tk + 1);
      WAITVM(6);                 // tile tk landed; tk+1 stays in flight
    } else {
      WAITVM(0);
    }
    __builtin_amdgcn_s_barrier();

    char* Abase = lds[cur];
    char* Bbase = lds[cur] + 32768;
    bf16x8 af[4][2], bf[4][2];
    // phase-A frags: af[0..1], bf[0..3]  (12 ds_read_b128)
#pragma unroll
    for (int mi = 0; mi < 2; ++mi) {
      int r = wm * 64 + mi * 16 + fr;
#pragma unroll
      for (int k = 0; k < 2; ++k)
        af[mi][k] = *(bf16x8*)(Abase + r * 128 + ((k * 64 + fq * 16) ^ ((r & 7) << 4)));
    }
#pragma unroll
    for (int ni = 0; ni < 4; ++ni) {
      int r = wn * 64 + ni * 16 + fr;
#pragma unroll
      for (int k = 0; k < 2; ++k)
        bf[ni][k] = *(bf16x8*)(Bbase + r * 128 + ((k * 64 + fq * 16) ^ ((r & 7) << 4)));
    }
    __builtin_amdgcn_sched_barrier(0);
    // phase-B frags: af[2..3]  (4 ds_read_b128) — land under phase-A MFMA
#pragma unroll
    for (int mi = 2; mi < 4; ++mi) {
      int r = wm * 64 + mi * 16 + fr;
#pragma unroll
      for (int k = 0; k < 2; ++k)
        af[mi][k] = *(bf16x8*)(Abase + r * 128 + ((k * 64 + fq * 16) ^ ((r & 7) << 4)));
    }
    WAITLG(4);                   // phase-A frags ready
    __builtin_amdgcn_s_setprio(1);
#pragma unroll
    for (int k = 0; k < 2; ++k)
#pragma unroll
      for (int mi = 0; mi < 2; ++mi)
#pragma unroll
        for (int ni = 0; ni < 4; ++ni)
          acc[mi][ni] = __builtin_amdgcn_mfma_f32_16x16x32_bf16(
              af[mi][k], bf[ni][k], acc[mi][ni], 0, 0, 0);
    __builtin_amdgcn_s_setprio(0);
    WAITLG(0);                   // phase-B frags ready
    __builtin_amdgcn_s_setprio(1);
#pragma unroll
    for (int k = 0; k < 2; ++k)
#pragma unroll
      for (int mi = 2; mi < 4; ++mi)
#pragma unroll
        for (int ni = 0; ni < 4; ++ni)
          acc[mi][ni] = __builtin_amdgcn_mfma_f32_16x16x32_bf16(
              af[mi][k], bf[ni][k], acc[mi][ni], 0, 0, 0);
    __builtin_amdgcn_s_setprio(0);
    __builtin_amdgcn_s_barrier();  // buf[cur] free to overwrite
  }

  // epilogue: D layout col=lane&15 (n), row=(lane>>4)*4+reg (m)  [m89]
#pragma unroll
  for (int ni = 0; ni < 4; ++ni) {
    int nloc = nloc0 + wn * 64 + ni * 16 + fr;
    float bv = 0.f;
    if constexpr (HAS_BIAS) bv = (bias + (size_t)e * N_)[nloc];
#pragma unroll
    for (int mi = 0; mi < 4; ++mi) {
      int m = grow0 + wm * 64 + mi * 16 + fq * 4;
#pragma unroll
      for (int j = 0; j < 4; ++j) {
        float val = acc[mi][ni][j] + bv;
        if constexpr (OUT_BF16)
          ((unsigned short*)Cv)[(size_t)(m + j) * N_ + nloc] = f2bf(val);
        else
          ((float*)Cv)[(size_t)(m + j) * N_ + nloc] = val;
      }
    }
  }
}

// ---------------------------------------------------------------------------
// Proven 2-phase 128x64 template — low-ws fallback paths only.
// ---------------------------------------------------------------------------
DEV int swz(int r, int cbyte) {
  return (r * 64 + cbyte) ^ (((r >> 1) & 7) << 4);
}

template <int K_, int N_, int NCT_, int AMODE, int BMODE, bool OUT_BF16,
          bool HAS_BIAS, int EDIV>
__global__ __launch_bounds__(256)
void gemm_expert(const void* __restrict__ Av, const void* __restrict__ Bv,
                 const float* __restrict__ bias, void* __restrict__ Cv) {
  __shared__ char lds[2][12288];

  const int t    = threadIdx.x;
  const int lane = t & 63;
  const int wv   = t >> 6;
  const int wr   = wv >> 1;
  const int wc   = wv & 1;
  const int fr   = lane & 15;
  const int fq   = lane >> 4;

  int bid = blockIdx.x;
  const int nwg = gridDim.x;
  if ((nwg & 7) == 0) bid = (bid & 7) * (nwg >> 3) + (bid >> 3);

  const int rt = bid / NCT_;
  const int ct = bid - rt * NCT_;

  int e;
  if constexpr (EDIV > 0) {
    e = rt / EDIV;
  } else {
    const int cums[9] = {0, 4, 12, 28, 60, 68, 72, 88, 96};
    e = 0;
#pragma unroll
    for (int i = 1; i < 8; ++i) e += (rt >= cums[i]) ? 1 : 0;
  }

  const int grow0 = rt * 128;
  const int nloc0 = ct * 64;

  f32x4 acc[4][2];
#pragma unroll
  for (int i = 0; i < 4; ++i)
#pragma unroll
    for (int j = 0; j < 2; ++j) acc[i][j] = (f32x4){0.f, 0.f, 0.f, 0.f};

  const unsigned short* Ab = (const unsigned short*)Av;
  const float*          Af = (const float*)Av;
  const unsigned short* Bb = (const unsigned short*)Bv + (size_t)e * N_ * K_;
  const float*          Bf = (const float*)Bv + (size_t)e * N_ * K_;

  auto stage = [&](int buf, int kb) {
    char* As = lds[buf];
    char* Bs = lds[buf] + 8192;
    if constexpr (AMODE == 1) {
#pragma unroll
      for (int s = 0; s < 2; ++s) {
        int o = (wv * 2 + s) * 1024 + lane * 16;
        int p = o ^ (((o >> 7) & 7) << 4);
        gld_lds16(Ab + (size_t)(grow0 + (p >> 6)) * K_ + kb + ((p & 63) >> 1),
                  As + (wv * 2 + s) * 1024);
      }
    } else {
#pragma unroll
      for (int it = 0; it < 4; ++it) {
        int q = t + it * 256, r = q >> 3, c = (q & 7) * 4;
        float4 f = *(const float4*)(Af + (size_t)(grow0 + r) * K_ + kb + c);
        ushort4 v = {f2bf(f.x), f2bf(f.y), f2bf(f.z), f2bf(f.w)};
        *(ushort4*)(As + swz(r, c * 2)) = v;
      }
    }
    if constexpr (BMODE == 1) {
      int o = wv * 1024 + lane * 16;
      int p = o ^ (((o >> 7) & 7) << 4);
      gld_lds16(Bb + (size_t)(nloc0 + (p >> 6)) * K_ + kb + ((p & 63) >> 1),
                Bs + wv * 1024);
    } else {
#pragma unroll
      for (int it = 0; it < 2; ++it) {
        int q = t + it * 256, r = q >> 3, c = (q & 7) * 4;
        float4 f = *(const float4*)(Bf + (size_t)(nloc0 + r) * K_ + kb + c);
        ushort4 v = {f2bf(f.x), f2bf(f.y), f2bf(f.z), f2bf(f.w)};
        *(ushort4*)(Bs + swz(r, c * 2)) = v;
      }
    }
  };

  auto compute = [&](int buf) {
    char* As = lds[buf];
    char* Bs = lds[buf] + 8192;
    bf16x8 af[4], bfg[2];
#pragma unroll
    for (int mi = 0; mi < 4; ++mi)
      af[mi] = *(bf16x8*)(As + swz(wr * 64 + mi * 16 + fr, fq * 16));
#pragma unroll
    for (int ni = 0; ni < 2; ++ni)
      bfg[ni] = *(bf16x8*)(Bs + swz(wc * 32 + ni * 16 + fr, fq * 16));
#pragma unroll
    for (int mi = 0; mi < 4; ++mi)
#pragma unroll
      for (int ni = 0; ni < 2; ++ni)
        acc[mi][ni] = __builtin_amdgcn_mfma_f32_16x16x32_bf16(
            af[mi], bfg[ni], acc[mi][ni], 0, 0, 0);
  };

  int cur = 0;
  stage(0, 0);
  __syncthreads();
#pragma unroll 2
  for (int kb = 32; kb < K_; kb += 32) {
    stage(cur ^ 1, kb);
    compute(cur);
    __syncthreads();
    cur ^= 1;
  }
  compute(cur);

#pragma unroll
  for (int ni = 0; ni < 2; ++ni) {
    int nloc = nloc0 + wc * 32 + ni * 16 + fr;
    float bv = 0.f;
    if constexpr (HAS_BIAS) bv = (bias + (size_t)e * N_)[nloc];
#pragma unroll
    for (int mi = 0; mi < 4; ++mi) {
      int m = grow0 + wr * 64 + mi * 16 + fq * 4;
#pragma unroll
      for (int j = 0; j < 4; ++j) {
        float val = acc[mi][ni][j] + bv;
        if constexpr (OUT_BF16)
          ((unsigned short*)Cv)[(size_t)(m + j) * N_ + nloc] = f2bf(val);
        else
          ((float*)Cv)[(size_t)(m + j) * N_ + nloc] = val;
      }
    }
  }
}

// w1 (E,4096,1024) f32 -> w1t (E,1024,4096) bf16, 64x64 tiles via LDS
__global__ __launch_bounds__(256)
void transpose_w1(const float* __restrict__ w1, unsigned short* __restrict__ w1t) {
  __shared__ unsigned short tl[64 * 68];
  int b = blockIdx.x;
  int jt = b & 15, kt = (b >> 4) & 63, e = b >> 10;
  const float* src = w1 + ((size_t)e * 4096 + kt * 64) * 1024 + jt * 64;
  int t = threadIdx.x;
#pragma unroll
  for (int it = 0; it < 4; ++it) {
    int q = t + it * 256, kr = q >> 4, jc = (q & 15) * 4;
    float4 f = *(const float4*)(src + (size_t)kr * 1024 + jc);
    ushort4 v = {f2bf(f.x), f2bf(f.y), f2bf(f.z), f2bf(f.w)};
    *(ushort4*)&tl[kr * 68 + jc] = v;
  }
  __syncthreads();
  unsigned short* dst = w1t + ((size_t)e * 1024 + jt * 64) * 4096 + kt * 64;
#pragma unroll
  for (int it = 0; it < 4; ++it) {
    int q = t + it * 256, jr = q >> 4, kc = (q & 15) * 4;
    ushort4 v = {tl[(kc + 0) * 68 + jr], tl[(kc + 1) * 68 + jr],
                 tl[(kc + 2) * 68 + jr], tl[(kc + 3) * 68 + jr]};
    *(ushort4*)(dst + (size_t)jr * 4096 + kc) = v;
  }
}

// per-row (e*1024+i): optional w2->bf16 convert + bc[row] = w2[row]·b1[e] + b2[row]
template <bool STORE_BF>
__global__ __launch_bounds__(256)
void conv_w2_bias(const float* __restrict__ w2, const float* __restrict__ b1,
                  const float* __restrict__ b2, unsigned short* __restrict__ w2bf,
                  float* __restrict__ bc) {
  int row = blockIdx.x, e = row >> 10, t = threadIdx.x;
  const float* src = w2 + (size_t)row * 4096;
  const float* b1e = b1 + (size_t)e * 4096;
  float acc = 0.f;
#pragma unroll
  for (int it = 0; it < 4; ++it) {
    int c = (t + it * 256) * 4;
    float4 f = *(const float4*)(src + c);
    float4 g = *(const float4*)(b1e + c);
    acc += f.x * g.x + f.y * g.y + f.z * g.z + f.w * g.w;
    if constexpr (STORE_BF) {
      ushort4 v = {f2bf(f.x), f2bf(f.y), f2bf(f.z), f2bf(f.w)};
      *(ushort4*)(w2bf + (size_t)row * 4096 + c) = v;
    }
  }
#pragma unroll
  for (int o = 32; o > 0; o >>= 1) acc += __shfl_down(acc, o);
  __shared__ float red[4];
  if ((t & 63) == 0) red[t >> 6] = acc;
  __syncthreads();
  if (t == 0) bc[row] = red[0] + red[1] + red[2] + red[3] + b2[row];
}

__global__ __launch_bounds__(256)
void conv_f32_bf16(const float* __restrict__ in, unsigned short* __restrict__ out,
                   int n4) {
  for (int i = blockIdx.x * 256 + threadIdx.x; i < n4; i += gridDim.x * 256) {
    float4 f = *(const float4*)(in + (size_t)i * 4);
    ushort4 v = {f2bf(f.x), f2bf(f.y), f2bf(f.z), f2bf(f.w)};
    *(ushort4*)(out + (size_t)i * 4) = v;
  }
}

extern "C" void kernel_launch(void* const* d_in, const int* in_sizes, int n_in,
                              void* d_out, int out_size, void* d_ws, size_t ws_size,
                              hipStream_t stream) {
  const float* x  = (const float*)d_in[0];   // (12288, 1024)
  const float* w1 = (const float*)d_in[1];   // (8, 4096, 1024)
  const float* b1 = (const float*)d_in[2];   // (8, 4096)
  const float* w2 = (const float*)d_in[3];   // (8, 1024, 4096)
  const float* b2 = (const float*)d_in[4];   // (8, 1024)

  char* ws = (char*)d_ws;
  unsigned short* w1t = (unsigned short*)ws;              // 64 MiB
  const size_t NEED_T2 = 151126016, NEED_T3 = 176291840;

  if (ws_size >= NEED_T2) {
    unsigned short* w2bf = (unsigned short*)(ws + 67108864);   // 64 MiB
    unsigned short* Wc   = (unsigned short*)(ws + 134217728);  // 16 MiB
    float*          bc   = (float*)(ws + 150994944);           // 32 KiB

    transpose_w1<<<8192, 256, 0, stream>>>(w1, w1t);
    conv_w2_bias<true><<<8192, 256, 0, stream>>>(w2, b1, b2, w2bf, bc);
    // Wc[e] = w2bf[e] @ w1t[e]^T : M=8192, N=1024, K=4096
    gemm8<4096, 1024, true, false, 4>
        <<<256, 512, 0, stream>>>(w2bf, w1t, nullptr, Wc);
    if (ws_size >= NEED_T3) {
      unsigned short* xbf = (unsigned short*)(ws + 151126016);
      conv_f32_bf16<<<2048, 256, 0, stream>>>(x, xbf, 12288 * 1024 / 4);
      gemm8<1024, 1024, false, true, 0>
          <<<384, 512, 0, stream>>>(xbf, Wc, bc, (float*)d_out);
    } else {
      gemm_expert<1024, 1024, 16, 0, 1, false, true, 0>
          <<<1536, 256, 0, stream>>>(x, Wc, bc, d_out);
    }
  } else {
    // P2 fallback: no w2bf materialization (84 MiB ws)
    unsigned short* Wc = (unsigned short*)(ws + 67108864);
    float*          bc = (float*)(ws + 83886080);

    transpose_w1<<<8192, 256, 0, stream>>>(w1, w1t);
    conv_w2_bias<false><<<8192, 256, 0, stream>>>(w2, b1, b2, nullptr, bc);
    gemm_expert<4096, 1024, 16, 0, 1, true, false, 8>
        <<<1024, 256, 0, stream>>>(w2, w1t, nullptr, Wc);
    gemm_expert<1024, 1024, 16, 0, 1, false, true, 0>
        <<<1536, 256, 0, stream>>>(x, Wc, bc, d_out);
  }
}